// Round 16
// baseline (160.317 us; speedup 1.0000x reference)
//
#include <hip/hip_runtime.h>
#include <hip/hip_bf16.h>

#define BSZ 2
#define NADJ 2
#define NN 2048
#define DE 64
#define HH 8
#define F1 64
#define NF 192   // 3*DE
#define K1 512   // HH*F1
#define LOG2E 1.4426950408889634f

typedef short s16x8 __attribute__((ext_vector_type(8)));
typedef unsigned short u16x8 __attribute__((ext_vector_type(8)));
typedef float f32x4 __attribute__((ext_vector_type(4)));

// async global->LDS, 16B per lane; LDS dest = uniform base + lane*16 (linear)
#define GLOAD_LDS16(gp, lp)                                                    \
  __builtin_amdgcn_global_load_lds(                                            \
      (const __attribute__((address_space(1))) unsigned int*)(const void*)(gp),\
      (__attribute__((address_space(3))) unsigned int*)(void*)(lp), 16, 0, 0)

__device__ __forceinline__ unsigned short f2b(float x) {
  union { float f; unsigned int u; } v; v.f = x;
  unsigned int r = v.u + 0x7fffu + ((v.u >> 16) & 1u);
  return (unsigned short)(r >> 16);
}
__device__ __forceinline__ float b2f(unsigned short u) {
  union { unsigned int u; float f; } v; v.u = ((unsigned int)u) << 16;
  return v.f;
}

// XOR-swizzled LDS read for MFMA fragments (layout produced by pre-swizzled
// global source + linear global_load_lds dest): byte ^= (row&7)<<4.
__device__ __forceinline__ const s16x8* tile_read_ptr(const unsigned short* lds,
                                                      int row, int kbyte) {
  return (const s16x8*)((const char*)lds + row * 128 + (kbyte ^ ((row & 7) << 4)));
}

// ---------------- build feat = [emb0[v], emb1[v], local_emb] (bf16) ---------
__global__ __launch_bounds__(256) void k_build_feat(
    const int* __restrict__ vert, const float* __restrict__ lemb,
    const float* __restrict__ emb0, const float* __restrict__ emb1,
    unsigned short* __restrict__ featB) {
  int idx = blockIdx.x * 256 + threadIdx.x;          // over BSZ*NN*NF
  int f = idx % NF;
  int bn = idx / NF;
  int v = vert[bn];
  float val;
  if (f < 64)       val = emb0[v * 64 + f];
  else if (f < 128) val = emb1[v * 64 + (f - 64)];
  else              val = lemb[bn * 64 + (f - 128)];
  featB[idx] = f2b(val);
}

// ---------------- adjacency ballot bitmask ----------------------------------
__global__ __launch_bounds__(256) void k_bits(
    const float* __restrict__ hg, unsigned long long* __restrict__ bits) {
  size_t idx = (size_t)blockIdx.x * 256 + threadIdx.x;   // over BSZ*NADJ*NN*NN
  float a = hg[idx];
  unsigned long long m = __ballot(a > 0.f);
  if ((threadIdx.x & 63) == 0) bits[idx >> 6] = m;
}

// ---------------- transpose-cast src[plane][R][64] f32 -> dst[plane][64][R] bf16
__global__ __launch_bounds__(256) void k_tcast(
    const float* __restrict__ src, unsigned short* __restrict__ dst, int R) {
  __shared__ unsigned short tr[64][72];
  int k0 = blockIdx.x * 64;
  int plane = blockIdx.y;
  const float* s = src + (size_t)plane * R * 64;
  unsigned short* d = dst + (size_t)plane * 64 * R;
  int t = threadIdx.x;
#pragma unroll
  for (int q = 0; q < 4; ++q) {
    int e = q * 256 + t;
    int kr = e >> 4, oc = (e & 15) * 4;
    float4 v = *(const float4*)&s[(size_t)(k0 + kr) * 64 + oc];
    tr[oc + 0][kr] = f2b(v.x);
    tr[oc + 1][kr] = f2b(v.y);
    tr[oc + 2][kr] = f2b(v.z);
    tr[oc + 3][kr] = f2b(v.w);
  }
  __syncthreads();
#pragma unroll
  for (int q = 0; q < 2; ++q) {
    int e = q * 256 + t;
    int o = e >> 3, j8 = (e & 7) * 8;
    *(u16x8*)&d[(size_t)o * R + k0 + j8] = *(const u16x8*)&tr[o][j8];
  }
}

// ---------------- fused GEMM (256t, K=NF, merged r): hpT + exp(s),exp(d) ----
// A/B staged via global_load_lds with pre-swizzled source.
// grid (NN/64, NADJ*HH, BSZ).  dT: u32 [P][h][n] = {bf16(Ed)<<16 | bf16(Ed2)}.
template <int K>
__global__ __launch_bounds__(256) void k_gemm_fused(
    const unsigned short* __restrict__ A, const unsigned short* __restrict__ Bw,
    const float* __restrict__ a_src, const float* __restrict__ a_dst,
    unsigned short* __restrict__ hpT, float2* __restrict__ sT,
    unsigned int* __restrict__ dT) {
  __shared__ unsigned short a_lds[2][64 * 64];
  __shared__ unsigned short b_lds[2][64 * 64];
  int tile = blockIdx.x, rh = blockIdx.y, b = blockIdx.z;
  int h = rh & 7, P = b * NADJ + (rh >> 3);
  int t = threadIdx.x, lane = t & 63, wv = t >> 6;
  const unsigned short* Ab = A + ((size_t)b * NN + tile * 64) * K;
  const unsigned short* Bb = Bw + (size_t)rh * 64 * K;
  const int NT = K / 64;
  // pre-swizzled source offsets (2 chunks/thread/operand)
  int i0 = t, i1 = 256 + t;
  int o0 = i0 >> 3, o1 = i1 >> 3;
  size_t s0 = (size_t)o0 * K + (size_t)(((i0 & 7) ^ (o0 & 7)) * 8);
  size_t s1 = (size_t)o1 * K + (size_t)(((i1 & 7) ^ (o1 & 7)) * 8);
  int db0 = (wv * 64) * 8, db1 = (256 + wv * 64) * 8;   // LDS granule bases

  GLOAD_LDS16(Ab + s0, a_lds[0] + db0);
  GLOAD_LDS16(Ab + s1, a_lds[0] + db1);
  GLOAD_LDS16(Bb + s0, b_lds[0] + db0);
  GLOAD_LDS16(Bb + s1, b_lds[0] + db1);
  __syncthreads();
  f32x4 acc[4] = {};
  int rowA = wv * 16 + (lane & 15);
  int rowB0 = lane & 15;
  int kb2 = (lane >> 4) * 16;
  for (int it = 0; it < NT; ++it) {
    int buf = it & 1;
    if (it + 1 < NT) {
      const unsigned short* As = Ab + (it + 1) * 64;
      const unsigned short* Bs = Bb + (it + 1) * 64;
      GLOAD_LDS16(As + s0, a_lds[buf ^ 1] + db0);
      GLOAD_LDS16(As + s1, a_lds[buf ^ 1] + db1);
      GLOAD_LDS16(Bs + s0, b_lds[buf ^ 1] + db0);
      GLOAD_LDS16(Bs + s1, b_lds[buf ^ 1] + db1);
    }
#pragma unroll
    for (int kk = 0; kk < 2; ++kk) {
      s16x8 av = *tile_read_ptr(a_lds[buf], rowA, kk * 64 + kb2);
#pragma unroll
      for (int nf = 0; nf < 4; ++nf) {
        s16x8 bv = *tile_read_ptr(b_lds[buf], nf * 16 + rowB0, kk * 64 + kb2);
        acc[nf] = __builtin_amdgcn_mfma_f32_16x16x32_bf16(av, bv, acc[nf], 0, 0, 0);
      }
    }
    __syncthreads();
  }
  // ---- epilogue 1 ----
  float sp[4] = {}, dp[4] = {};
#pragma unroll
  for (int nf = 0; nf < 4; ++nf) {
    int c = nf * 16 + (lane & 15);
    float as = a_src[rh * 64 + c], ad = a_dst[rh * 64 + c];
#pragma unroll
    for (int reg = 0; reg < 4; ++reg) {
      float x = acc[nf][reg];
      x = fminf(fmaxf(x, -30.f), 30.f);
      float e2 = __builtin_amdgcn_exp2f(x * (2.f * LOG2E));
      float th = (e2 - 1.f) * __builtin_amdgcn_rcpf(e2 + 1.f);
      sp[reg] += th * as;
      dp[reg] += th * ad;
    }
  }
#pragma unroll
  for (int reg = 0; reg < 4; ++reg) {
#pragma unroll
    for (int off = 8; off; off >>= 1) {
      sp[reg] += __shfl_xor(sp[reg], off);
      dp[reg] += __shfl_xor(dp[reg], off);
    }
  }
  if ((lane & 15) == 0) {
#pragma unroll
    for (int reg = 0; reg < 4; ++reg) {
      int m = tile * 64 + wv * 16 + (lane >> 4) * 4 + reg;
      float sv = sp[reg] * LOG2E, dv = dp[reg] * LOG2E;
      sT[(size_t)P * NN * HH + (size_t)m * HH + h] =
          make_float2(__builtin_amdgcn_exp2f(sv), __builtin_amdgcn_exp2f(0.2f * sv));
      float Ed = __builtin_amdgcn_exp2f(dv), Ed2 = __builtin_amdgcn_exp2f(0.2f * dv);
      dT[((size_t)P * HH + h) * NN + m] =
          ((unsigned int)f2b(Ed) << 16) | (unsigned int)f2b(Ed2);
    }
  }
  // ---- epilogue 2: transpose-cast to hpT via LDS bounce -------------------
  unsigned short* tr = a_lds[0];
#pragma unroll
  for (int nf = 0; nf < 4; ++nf) {
    int c = nf * 16 + (lane & 15);
#pragma unroll
    for (int reg = 0; reg < 4; ++reg) {
      int m = wv * 16 + (lane >> 4) * 4 + reg;
      tr[c * 76 + m] = f2b(acc[nf][reg]);
    }
  }
  __syncthreads();
  unsigned short* dst = hpT + ((size_t)P * HH + h) * 64 * NN + tile * 64;
#pragma unroll
  for (int q = 0; q < 2; ++q) {
    int e = q * 256 + t;
    int o = e >> 3, j8 = (e & 7) * 8;
    u16x8 v;
#pragma unroll
    for (int z = 0; z < 8; ++z) v[z] = tr[o * 76 + j8 + z];
    *(u16x8*)&dst[(size_t)o * NN + j8] = v;
  }
}

// ---------------- fused GEMM K=512, 512t, K-split, merged r -----------------
// grid (NN/64, HH, BSZ*NADJ).  DMA staging, pre-swizzled source.
__global__ __launch_bounds__(512) void k_gemm_fused_ks(
    const unsigned short* __restrict__ A, const unsigned short* __restrict__ Bw,
    const float* __restrict__ a_src, const float* __restrict__ a_dst,
    unsigned short* __restrict__ hpT, float2* __restrict__ sT,
    unsigned int* __restrict__ dT) {
  __shared__ unsigned short a_lds[2][2][64 * 64];   // [group][dbuf]
  __shared__ unsigned short b_lds[2][2][64 * 64];
  const int K = K1;
  int tile = blockIdx.x, h = blockIdx.y, P = blockIdx.z;
  int rh = (P & 1) * HH + h;
  int t = threadIdx.x, lane = t & 63;
  int wid = t >> 6, g = wid >> 2, wv = wid & 3;
  int tg = t & 255;
  const unsigned short* Ab = A + ((size_t)P * NN + tile * 64) * K + g * 256;
  const unsigned short* Bb = Bw + (size_t)rh * 64 * K + g * 256;
  const int NT = 4;
  int i0 = tg, i1 = 256 + tg;
  int o0 = i0 >> 3, o1 = i1 >> 3;
  size_t s0 = (size_t)o0 * K + (size_t)(((i0 & 7) ^ (o0 & 7)) * 8);
  size_t s1 = (size_t)o1 * K + (size_t)(((i1 & 7) ^ (o1 & 7)) * 8);
  int db0 = (wv * 64) * 8, db1 = (256 + wv * 64) * 8;

  GLOAD_LDS16(Ab + s0, a_lds[g][0] + db0);
  GLOAD_LDS16(Ab + s1, a_lds[g][0] + db1);
  GLOAD_LDS16(Bb + s0, b_lds[g][0] + db0);
  GLOAD_LDS16(Bb + s1, b_lds[g][0] + db1);
  __syncthreads();
  f32x4 acc[4] = {};
  int rowA = wv * 16 + (lane & 15);
  int rowB0 = lane & 15;
  int kb2 = (lane >> 4) * 16;
  for (int it = 0; it < NT; ++it) {
    int buf = it & 1;
    if (it + 1 < NT) {
      const unsigned short* As = Ab + (it + 1) * 64;
      const unsigned short* Bs = Bb + (it + 1) * 64;
      GLOAD_LDS16(As + s0, a_lds[g][buf ^ 1] + db0);
      GLOAD_LDS16(As + s1, a_lds[g][buf ^ 1] + db1);
      GLOAD_LDS16(Bs + s0, b_lds[g][buf ^ 1] + db0);
      GLOAD_LDS16(Bs + s1, b_lds[g][buf ^ 1] + db1);
    }
#pragma unroll
    for (int kk = 0; kk < 2; ++kk) {
      s16x8 av = *tile_read_ptr(a_lds[g][buf], rowA, kk * 64 + kb2);
#pragma unroll
      for (int nf = 0; nf < 4; ++nf) {
        s16x8 bv = *tile_read_ptr(b_lds[g][buf], nf * 16 + rowB0, kk * 64 + kb2);
        acc[nf] = __builtin_amdgcn_mfma_f32_16x16x32_bf16(av, bv, acc[nf], 0, 0, 0);
      }
    }
    __syncthreads();
  }
  // ---- combine partials ----
  float* comb = (float*)&a_lds[0][0][0];
  if (g == 1) {
    float* dst = comb + (wv * 64 + lane) * 17;
#pragma unroll
    for (int nf = 0; nf < 4; ++nf)
#pragma unroll
      for (int reg = 0; reg < 4; ++reg) dst[nf * 4 + reg] = acc[nf][reg];
  }
  __syncthreads();
  if (g == 0) {
    const float* srcp = comb + (wv * 64 + lane) * 17;
#pragma unroll
    for (int nf = 0; nf < 4; ++nf)
#pragma unroll
      for (int reg = 0; reg < 4; ++reg) acc[nf][reg] += srcp[nf * 4 + reg];
    float sp[4] = {}, dp[4] = {};
#pragma unroll
    for (int nf = 0; nf < 4; ++nf) {
      int c = nf * 16 + (lane & 15);
      float as = a_src[rh * 64 + c], ad = a_dst[rh * 64 + c];
#pragma unroll
      for (int reg = 0; reg < 4; ++reg) {
        float x = acc[nf][reg];
        x = fminf(fmaxf(x, -30.f), 30.f);
        float e2 = __builtin_amdgcn_exp2f(x * (2.f * LOG2E));
        float th = (e2 - 1.f) * __builtin_amdgcn_rcpf(e2 + 1.f);
        sp[reg] += th * as;
        dp[reg] += th * ad;
      }
    }
#pragma unroll
    for (int reg = 0; reg < 4; ++reg) {
#pragma unroll
      for (int off = 8; off; off >>= 1) {
        sp[reg] += __shfl_xor(sp[reg], off);
        dp[reg] += __shfl_xor(dp[reg], off);
      }
    }
    if ((lane & 15) == 0) {
#pragma unroll
      for (int reg = 0; reg < 4; ++reg) {
        int m = tile * 64 + wv * 16 + (lane >> 4) * 4 + reg;
        float sv = sp[reg] * LOG2E, dv = dp[reg] * LOG2E;
        sT[(size_t)P * NN * HH + (size_t)m * HH + h] =
            make_float2(__builtin_amdgcn_exp2f(sv), __builtin_amdgcn_exp2f(0.2f * sv));
        float Ed = __builtin_amdgcn_exp2f(dv), Ed2 = __builtin_amdgcn_exp2f(0.2f * dv);
        dT[((size_t)P * HH + h) * NN + m] =
            ((unsigned int)f2b(Ed) << 16) | (unsigned int)f2b(Ed2);
      }
    }
    unsigned short* tr = (unsigned short*)&b_lds[0][0][0];
#pragma unroll
    for (int nf = 0; nf < 4; ++nf) {
      int c = nf * 16 + (lane & 15);
#pragma unroll
      for (int reg = 0; reg < 4; ++reg) {
        int m = wv * 16 + (lane >> 4) * 4 + reg;
        tr[c * 76 + m] = f2b(acc[nf][reg]);
      }
    }
  }
  __syncthreads();
  if (g == 0) {
    const unsigned short* tr = (const unsigned short*)&b_lds[0][0][0];
    unsigned short* dst = hpT + ((size_t)P * HH + h) * 64 * NN + tile * 64;
#pragma unroll
    for (int q = 0; q < 2; ++q) {
      int e = q * 256 + tg;
      int o = e >> 3, j8 = (e & 7) * 8;
      u16x8 v;
#pragma unroll
      for (int z = 0; z < 8; ++z) v[z] = tr[o * 76 + j8 + z];
      *(u16x8*)&dst[(size_t)o * NN + j8] = v;
    }
  }
}

// ---------------- PV (16x16x32, 256t: 2 row-waves(32r) x 2 j-halves) --------
// Each B-frag LDS read feeds BOTH rowgroups (halved LDS amplification).
// hp via global_load_lds (pre-swizzled src); d preloaded packed u32;
// weight = max(Es*Ed, Es2*Ed2) & mask; l via ones-column MFMA; T5 setprio.
// LDS 40KB -> 4 blocks/CU. grid (NN/64, HH, NP).
// MODE 0: aoutB bf16 [P,h,n,o].  MODE 1: hmidB bf16 [P,n,h*64+o] with ELU.
template <int MODE>
__global__ __launch_bounds__(256) void k_pv(
    const unsigned long long* __restrict__ bits,
    const unsigned short* __restrict__ hpT,
    const float2* __restrict__ sT, const unsigned int* __restrict__ dT,
    unsigned short* __restrict__ outB) {
  __shared__ unsigned short hp_lds[2][2][64 * 64];   // [g][dbuf] 32KB
  __shared__ unsigned int d_all[2][1024];            // packed d halves, 8KB
  int i0 = blockIdx.x * 64, h = blockIdx.y, P = blockIdx.z;
  int t = threadIdx.x, lane = t & 63;
  int wid = t >> 6;          // 0..3
  int rw = wid & 1;          // row-wave: rows rw*32 .. rw*32+31
  int g  = wid >> 1;         // j-half
  int tg = t & 127;          // staging index within j-half (= rw*64+lane)
  int kb = (lane >> 4) * 8;
  int row0 = rw * 32 + (lane & 15);
  float2 se0 = sT[(size_t)P * NN * HH + (size_t)(i0 + row0) * HH + h];
  float2 se1 = sT[(size_t)P * NN * HH + (size_t)(i0 + row0 + 16) * HH + h];
  const unsigned long long* brow0 =
      bits + ((size_t)P * NN + i0 + row0) * 32 + g * 16;
  const unsigned long long* brow1 = brow0 + 16 * 32;
  const unsigned short* hpTb = hpT + ((size_t)P * HH + h) * 64 * NN + g * 1024;
  const unsigned int* dTb = dT + ((size_t)P * HH + h) * NN + g * 1024;
  f32x4 acc[2][4] = {};
  f32x4 accl0 = {}, accl1 = {};
  const short ONE = (short)0x3F80;
  const s16x8 ones = {ONE, ONE, ONE, ONE, ONE, ONE, ONE, ONE};

  // staging: 4 chunks of 16B/thread/tile; pre-swizzled global source
  size_t soff0, soff1, soff2, soff3;
  {
    int idx, o;
    idx = 0 * 128 + tg; o = idx >> 3;
    soff0 = (size_t)o * NN + (size_t)((((idx & 7) ^ (o & 7))) * 8);
    idx = 1 * 128 + tg; o = idx >> 3;
    soff1 = (size_t)o * NN + (size_t)((((idx & 7) ^ (o & 7))) * 8);
    idx = 2 * 128 + tg; o = idx >> 3;
    soff2 = (size_t)o * NN + (size_t)((((idx & 7) ^ (o & 7))) * 8);
    idx = 3 * 128 + tg; o = idx >> 3;
    soff3 = (size_t)o * NN + (size_t)((((idx & 7) ^ (o & 7))) * 8);
  }
  int db0 = (0 * 128 + rw * 64) * 8;
  int db1 = (1 * 128 + rw * 64) * 8;
  int db2 = (2 * 128 + rw * 64) * 8;
  int db3 = (3 * 128 + rw * 64) * 8;

  // prologue: DMA tile 0; preload ENTIRE d half (4KB per half)
  {
    unsigned short* db = hp_lds[g][0];
    GLOAD_LDS16(hpTb + soff0, db + db0);
    GLOAD_LDS16(hpTb + soff1, db + db1);
    GLOAD_LDS16(hpTb + soff2, db + db2);
    GLOAD_LDS16(hpTb + soff3, db + db3);
  }
  {
    uint4 dv0 = *(const uint4*)&dTb[tg * 8];
    uint4 dv1 = *(const uint4*)&dTb[tg * 8 + 4];
    *(uint4*)&d_all[g][tg * 8] = dv0;
    *(uint4*)&d_all[g][tg * 8 + 4] = dv1;
  }
  unsigned long long bw0 = brow0[0], bw1 = brow1[0];
  __syncthreads();

  const int NT = 16;   // 16 tiles of 64 j per half
  for (int it = 0; it < NT; ++it) {
    int buf = it & 1;
    if (it + 1 < NT) {
      const unsigned short* src = hpTb + (it + 1) * 64;
      unsigned short* db = hp_lds[g][buf ^ 1];
      GLOAD_LDS16(src + soff0, db + db0);
      GLOAD_LDS16(src + soff1, db + db1);
      GLOAD_LDS16(src + soff2, db + db2);
      GLOAD_LDS16(src + soff3, db + db3);
    }
    unsigned long long bwn0 = 0, bwn1 = 0;
    if (it + 1 < NT) { bwn0 = brow0[it + 1]; bwn1 = brow1[it + 1]; }
    union { unsigned int u[4]; s16x8 v; } af[2][2];   // [rg][kk]
#pragma unroll
    for (int kk = 0; kk < 2; ++kk) {
      const unsigned int* dpk = &d_all[g][it * 64 + kk * 32 + kb];
      uint4 p0 = *(const uint4*)(dpk);
      uint4 p1 = *(const uint4*)(dpk + 4);
      unsigned int pk8[8] = {p0.x, p0.y, p0.z, p0.w, p1.x, p1.y, p1.z, p1.w};
      unsigned int bs0 = (unsigned int)(bw0 >> (kk * 32 + kb));
      unsigned int bs1 = (unsigned int)(bw1 >> (kk * 32 + kb));
#pragma unroll
      for (int rg = 0; rg < 2; ++rg) {
        float Es  = rg ? se1.x : se0.x;
        float Es2 = rg ? se1.y : se0.y;
        unsigned int bs = rg ? bs1 : bs0;
        float w8[8];
#pragma unroll
        for (int c = 0; c < 8; ++c) {
          int msk = ((int)(bs << (31 - c))) >> 31;     // adj bit -> 0/-1
          unsigned int pm = pk8[c] & (unsigned int)msk;
          float Ed  = __uint_as_float(pm & 0xffff0000u);
          float Ed2 = __uint_as_float(pm << 16);
          w8[c] = fmaxf(Es * Ed, Es2 * Ed2);           // exp(leaky(s+d))
        }
#pragma unroll
        for (int p = 0; p < 4; ++p) {
          unsigned int pk;
          asm volatile("v_cvt_pk_bf16_f32 %0, %1, %2"
                       : "=v"(pk) : "v"(w8[2 * p]), "v"(w8[2 * p + 1]));
          af[rg][kk].u[p] = pk;
        }
      }
    }
    __builtin_amdgcn_s_setprio(1);
#pragma unroll
    for (int kk = 0; kk < 2; ++kk) {
#pragma unroll
      for (int nf = 0; nf < 4; ++nf) {
        s16x8 bv = *tile_read_ptr(hp_lds[g][buf], nf * 16 + (lane & 15),
                                  kk * 64 + (lane >> 4) * 16);
        acc[0][nf] = __builtin_amdgcn_mfma_f32_16x16x32_bf16(af[0][kk].v, bv, acc[0][nf], 0, 0, 0);
        acc[1][nf] = __builtin_amdgcn_mfma_f32_16x16x32_bf16(af[1][kk].v, bv, acc[1][nf], 0, 0, 0);
      }
      accl0 = __builtin_amdgcn_mfma_f32_16x16x32_bf16(af[0][kk].v, ones, accl0, 0, 0, 0);
      accl1 = __builtin_amdgcn_mfma_f32_16x16x32_bf16(af[1][kk].v, ones, accl1, 0, 0, 0);
    }
    __builtin_amdgcn_s_setprio(0);
    bw0 = bwn0; bw1 = bwn1;
    __syncthreads();
  }
  // ---- combine j-halves: g=1 -> LDS (stride-41 pad), g=0 adds + writes -----
  float* comb = (float*)&hp_lds[0][0][0];   // 128 threads x 41 floats = 21KB
  if (g == 1) {
    float* dst = comb + tg * 41;
#pragma unroll
    for (int rg = 0; rg < 2; ++rg)
#pragma unroll
      for (int nf = 0; nf < 4; ++nf)
#pragma unroll
        for (int reg = 0; reg < 4; ++reg)
          dst[rg * 16 + nf * 4 + reg] = acc[rg][nf][reg];
#pragma unroll
    for (int reg = 0; reg < 4; ++reg) {
      dst[32 + reg] = accl0[reg];
      dst[36 + reg] = accl1[reg];
    }
  }
  __syncthreads();
  if (g == 0) {
    const float* srcp = comb + tg * 41;
#pragma unroll
    for (int rg = 0; rg < 2; ++rg)
#pragma unroll
      for (int nf = 0; nf < 4; ++nf)
#pragma unroll
        for (int reg = 0; reg < 4; ++reg)
          acc[rg][nf][reg] += srcp[rg * 16 + nf * 4 + reg];
#pragma unroll
    for (int reg = 0; reg < 4; ++reg) {
      accl0[reg] += srcp[32 + reg];
      accl1[reg] += srcp[36 + reg];
    }
    int col = lane & 15, r0g = (lane >> 4) * 4;
#pragma unroll
    for (int rg = 0; rg < 2; ++rg) {
#pragma unroll
      for (int reg = 0; reg < 4; ++reg) {
        int m = rw * 32 + rg * 16 + r0g + reg;
        float lv = rg ? accl1[reg] : accl0[reg];
        float linv = 1.0f / lv;
        if (MODE == 0) {
          size_t ob = (((size_t)P * HH + h) * NN + i0 + m) * 64 + col;
#pragma unroll
          for (int nf = 0; nf < 4; ++nf)
            outB[ob + nf * 16] = f2b(acc[rg][nf][reg] * linv);
        } else {
          size_t ob = ((size_t)P * NN + i0 + m) * K1 + h * 64 + col;
#pragma unroll
          for (int nf = 0; nf < 4; ++nf) {
            float v = acc[rg][nf][reg] * linv;
            v = v > 0.f ? v : (__builtin_amdgcn_exp2f(v * LOG2E) - 1.f);
            outB[ob + nf * 16] = f2b(v);
          }
        }
      }
    }
  }
}

// ---------------- mean over heads → seq[b,n,r,:] (bf16 in, merged r) --------
__global__ __launch_bounds__(256) void k_mean(
    const unsigned short* __restrict__ in, float* __restrict__ seq) {
  int idx = blockIdx.x * 256 + threadIdx.x;   // over BSZ*NADJ*NN*8
  int o8 = (idx & 7) * 8;
  int n = (idx >> 3) & (NN - 1);
  int P = idx >> 14;
  int b = P >> 1, r = P & 1;
  float acc[8] = {};
#pragma unroll
  for (int h = 0; h < HH; ++h) {
    u16x8 v = *(const u16x8*)&in[(((size_t)P * HH + h) * NN + n) * 64 + o8];
#pragma unroll
    for (int z = 0; z < 8; ++z) acc[z] += b2f((unsigned short)v[z]);
  }
  float* dst = &seq[(((size_t)b * NN + n) * NADJ + r) * 64 + o8];
#pragma unroll
  for (int z = 0; z < 8; ++z) dst[z] = acc[z] * 0.125f;
}

// ---------------- final: fproj (feat@aw1) + fusion + log_softmax ------------
__global__ __launch_bounds__(256) void k_fuse(
    const unsigned short* __restrict__ featB, const float* __restrict__ aw1,
    const float* __restrict__ seq, const float* __restrict__ aw2,
    const float* __restrict__ am, float* __restrict__ outp) {
  __shared__ float w2[64][65];
  __shared__ float a1[NF][64];
  __shared__ float amv[64];
  __shared__ unsigned short feat_l[4][NF];
  __shared__ float seq_lds[4][NADJ][64];
  int t = threadIdx.x;
#pragma unroll
  for (int q = 0; q < 16; ++q) {
    int e = t + 256 * q;
    w2[e >> 6][e & 63] = aw2[e];
  }
  float* a1f = &a1[0][0];
#pragma unroll
  for (int q = 0; q < 12; ++q) {
    int e4 = (t + 256 * q) * 4;
    *(float4*)&a1f[e4] = *(const float4*)&aw1[e4];
  }
  if (t < 64) amv[t] = am[t];
  int wid = t >> 6, lane = t & 63;
  int bn = blockIdx.x * 4 + wid;               // over BSZ*NN
  if (lane < 24)
    *(u16x8*)&feat_l[wid][lane * 8] = *(const u16x8*)&featB[(size_t)bn * NF + lane * 8];
  float s0 = seq[((size_t)bn * NADJ + 0) * 64 + lane];
  float s1 = seq[((size_t)bn * NADJ + 1) * 64 + lane];
  seq_lds[wid][0][lane] = s0;
  seq_lds[wid][1][lane] = s1;
  __syncthreads();
  float f = 0.f;
#pragma unroll 4
  for (int kc = 0; kc < NF / 8; ++kc) {
    u16x8 fv = *(const u16x8*)&feat_l[wid][kc * 8];
#pragma unroll
    for (int z = 0; z < 8; ++z)
      f += b2f((unsigned short)fv[z]) * a1[kc * 8 + z][lane];
  }
  float q0 = f, q1 = f;
  for (int k = 0; k < 64; ++k) {
    float wv = w2[k][lane];
    q0 += seq_lds[wid][0][k] * wv;
    q1 += seq_lds[wid][1][k] * wv;
  }
  q0 = tanhf(q0); q1 = tanhf(q1);
  float sc0 = q0 * amv[lane], sc1 = q1 * amv[lane];
  for (int off = 32; off; off >>= 1) {
    sc0 += __shfl_xor(sc0, off);
    sc1 += __shfl_xor(sc1, off);
  }
  float mx = fmaxf(sc0, sc1);
  float e0 = __expf(sc0 - mx), e1 = __expf(sc1 - mx);
  float inv = 1.f / (e0 + e1);
  float fu = (e0 * inv) * s0 + (e1 * inv) * s1;
  float m = fu;
  for (int off = 32; off; off >>= 1) m = fmaxf(m, __shfl_xor(m, off));
  float ex = __expf(fu - m);
  float ssum = ex;
  for (int off = 32; off; off >>= 1) ssum += __shfl_xor(ssum, off);
  outp[(size_t)bn * 64 + lane] = fu - m - __logf(ssum);
}

extern "C" void kernel_launch(void* const* d_in, const int* in_sizes, int n_in,
                              void* d_out, int out_size, void* d_ws, size_t ws_size,
                              hipStream_t stream) {
  (void)in_sizes; (void)n_in; (void)out_size; (void)ws_size;
  const float* hg   = (const float*)d_in[0];
  const int*   vert = (const int*)d_in[1];
  const float* lemb = (const float*)d_in[2];
  const float* emb0 = (const float*)d_in[3];
  const float* emb1 = (const float*)d_in[4];
  const float* w_l0 = (const float*)d_in[5];
  const float* as0  = (const float*)d_in[6];
  const float* ad0  = (const float*)d_in[7];
  const float* w_l1 = (const float*)d_in[8];
  const float* as1  = (const float*)d_in[9];
  const float* ad1  = (const float*)d_in[10];
  const float* aw1  = (const float*)d_in[11];
  const float* aw2  = (const float*)d_in[12];
  const float* am   = (const float*)d_in[13];
  float* out = (float*)d_out;

  const int NP = BSZ * NADJ;   // 4 planes
  char* p = (char*)d_ws;
  unsigned short* hpT   = (unsigned short*)p;  p += (size_t)NP*HH*NN*64*2;    // 8MB
  unsigned short* aoutB = (unsigned short*)p;  p += (size_t)NP*HH*NN*64*2;    // 8MB
  unsigned short* hmidB = (unsigned short*)p;  p += (size_t)NP*NN*K1*2;       // 8MB
  unsigned short* featB = (unsigned short*)p;  p += (size_t)BSZ*NN*NF*2;      // 1.5MB
  unsigned short* wT0   = (unsigned short*)p;  p += (size_t)NADJ*HH*64*NF*2;
  unsigned short* wT1   = (unsigned short*)p;  p += (size_t)NADJ*HH*64*K1*2;
  float2* sT            = (float2*)p;          p += (size_t)NP*NN*HH*8;       // 1MB
  unsigned int* dT      = (unsigned int*)p;    p += (size_t)NP*HH*NN*4;       // 0.5MB
  unsigned long long* bits = (unsigned long long*)p; p += (size_t)NP*NN*(NN/64)*8;  // 2MB
  float* seq            = (float*)p;           p += (size_t)BSZ*NN*NADJ*64*4; // 2MB

  // one-time prep
  k_build_feat<<<(BSZ*NN*NF)/256, 256, 0, stream>>>(vert, lemb, emb0, emb1, featB);
  k_bits<<<(size_t)NP*NN*NN/256, 256, 0, stream>>>(hg, bits);
  k_tcast<<<dim3(NF/64, NADJ*HH), 256, 0, stream>>>(w_l0, wT0, NF);
  k_tcast<<<dim3(K1/64, NADJ*HH), 256, 0, stream>>>(w_l1, wT1, K1);

  // merged r=0/r=1 pipeline: 5 dispatches
  k_gemm_fused<NF><<<dim3(NN/64, NADJ*HH, BSZ), 256, 0, stream>>>(
      featB, wT0, as0, ad0, hpT, sT, dT);
  k_pv<1><<<dim3(NN/64, HH, NP), 256, 0, stream>>>(bits, hpT, sT, dT, hmidB);
  k_gemm_fused_ks<<<dim3(NN/64, HH, NP), 512, 0, stream>>>(
      hmidB, wT1, as1, ad1, hpT, sT, dT);
  k_pv<0><<<dim3(NN/64, HH, NP), 256, 0, stream>>>(bits, hpT, sT, dT, aoutB);
  k_mean<<<(NP*NN*8)/256, 256, 0, stream>>>(aoutB, seq);

  k_fuse<<<BSZ*NN/4, 256, 0, stream>>>(featB, aw1, seq, aw2, am, out);
}

// Round 17
// 156.256 us; speedup vs baseline: 1.0260x; 1.0260x over previous
//
#include <hip/hip_runtime.h>
#include <hip/hip_bf16.h>

#define BSZ 2
#define NADJ 2
#define NN 2048
#define DE 64
#define HH 8
#define F1 64
#define NF 192   // 3*DE
#define K1 512   // HH*F1
#define LOG2E 1.4426950408889634f

typedef short s16x8 __attribute__((ext_vector_type(8)));
typedef unsigned short u16x8 __attribute__((ext_vector_type(8)));
typedef float f32x4 __attribute__((ext_vector_type(4)));

// async global->LDS, 16B per lane; LDS dest = uniform base + lane*16 (linear)
#define GLOAD_LDS16(gp, lp)                                                    \
  __builtin_amdgcn_global_load_lds(                                            \
      (const __attribute__((address_space(1))) unsigned int*)(const void*)(gp),\
      (__attribute__((address_space(3))) unsigned int*)(void*)(lp), 16, 0, 0)

__device__ __forceinline__ unsigned short f2b(float x) {
  union { float f; unsigned int u; } v; v.f = x;
  unsigned int r = v.u + 0x7fffu + ((v.u >> 16) & 1u);
  return (unsigned short)(r >> 16);
}
__device__ __forceinline__ float b2f(unsigned short u) {
  union { unsigned int u; float f; } v; v.u = ((unsigned int)u) << 16;
  return v.f;
}

// XOR-swizzled LDS read for MFMA fragments (layout produced by pre-swizzled
// global source + linear global_load_lds dest): byte ^= (row&7)<<4.
__device__ __forceinline__ const s16x8* tile_read_ptr(const unsigned short* lds,
                                                      int row, int kbyte) {
  return (const s16x8*)((const char*)lds + row * 128 + (kbyte ^ ((row & 7) << 4)));
}

// ---------------- build feat = [emb0[v], emb1[v], local_emb] (bf16) ---------
__global__ __launch_bounds__(256) void k_build_feat(
    const int* __restrict__ vert, const float* __restrict__ lemb,
    const float* __restrict__ emb0, const float* __restrict__ emb1,
    unsigned short* __restrict__ featB) {
  int idx = blockIdx.x * 256 + threadIdx.x;          // over BSZ*NN*NF
  int f = idx % NF;
  int bn = idx / NF;
  int v = vert[bn];
  float val;
  if (f < 64)       val = emb0[v * 64 + f];
  else if (f < 128) val = emb1[v * 64 + (f - 64)];
  else              val = lemb[bn * 64 + (f - 128)];
  featB[idx] = f2b(val);
}

// ---------------- adjacency ballot bitmask ----------------------------------
__global__ __launch_bounds__(256) void k_bits(
    const float* __restrict__ hg, unsigned long long* __restrict__ bits) {
  size_t idx = (size_t)blockIdx.x * 256 + threadIdx.x;   // over BSZ*NADJ*NN*NN
  float a = hg[idx];
  unsigned long long m = __ballot(a > 0.f);
  if ((threadIdx.x & 63) == 0) bits[idx >> 6] = m;
}

// ---------------- transpose-cast src[plane][R][64] f32 -> dst[plane][64][R] bf16
__global__ __launch_bounds__(256) void k_tcast(
    const float* __restrict__ src, unsigned short* __restrict__ dst, int R) {
  __shared__ unsigned short tr[64][72];
  int k0 = blockIdx.x * 64;
  int plane = blockIdx.y;
  const float* s = src + (size_t)plane * R * 64;
  unsigned short* d = dst + (size_t)plane * 64 * R;
  int t = threadIdx.x;
#pragma unroll
  for (int q = 0; q < 4; ++q) {
    int e = q * 256 + t;
    int kr = e >> 4, oc = (e & 15) * 4;
    float4 v = *(const float4*)&s[(size_t)(k0 + kr) * 64 + oc];
    tr[oc + 0][kr] = f2b(v.x);
    tr[oc + 1][kr] = f2b(v.y);
    tr[oc + 2][kr] = f2b(v.z);
    tr[oc + 3][kr] = f2b(v.w);
  }
  __syncthreads();
#pragma unroll
  for (int q = 0; q < 2; ++q) {
    int e = q * 256 + t;
    int o = e >> 3, j8 = (e & 7) * 8;
    *(u16x8*)&d[(size_t)o * R + k0 + j8] = *(const u16x8*)&tr[o][j8];
  }
}

// ---------------- fused GEMM (256t, K=NF, merged r): hpT + exp(s),exp(d) ----
// A/B staged via global_load_lds with pre-swizzled source.
// grid (NN/64, NADJ*HH, BSZ).  dT: u32 [P][h][n] = {bf16(Ed)<<16 | bf16(Ed2)}.
template <int K>
__global__ __launch_bounds__(256) void k_gemm_fused(
    const unsigned short* __restrict__ A, const unsigned short* __restrict__ Bw,
    const float* __restrict__ a_src, const float* __restrict__ a_dst,
    unsigned short* __restrict__ hpT, float2* __restrict__ sT,
    unsigned int* __restrict__ dT) {
  __shared__ unsigned short a_lds[2][64 * 64];
  __shared__ unsigned short b_lds[2][64 * 64];
  int tile = blockIdx.x, rh = blockIdx.y, b = blockIdx.z;
  int h = rh & 7, P = b * NADJ + (rh >> 3);
  int t = threadIdx.x, lane = t & 63, wv = t >> 6;
  const unsigned short* Ab = A + ((size_t)b * NN + tile * 64) * K;
  const unsigned short* Bb = Bw + (size_t)rh * 64 * K;
  const int NT = K / 64;
  // pre-swizzled source offsets (2 chunks/thread/operand)
  int i0 = t, i1 = 256 + t;
  int o0 = i0 >> 3, o1 = i1 >> 3;
  size_t s0 = (size_t)o0 * K + (size_t)(((i0 & 7) ^ (o0 & 7)) * 8);
  size_t s1 = (size_t)o1 * K + (size_t)(((i1 & 7) ^ (o1 & 7)) * 8);
  int db0 = (wv * 64) * 8, db1 = (256 + wv * 64) * 8;   // LDS granule bases

  GLOAD_LDS16(Ab + s0, a_lds[0] + db0);
  GLOAD_LDS16(Ab + s1, a_lds[0] + db1);
  GLOAD_LDS16(Bb + s0, b_lds[0] + db0);
  GLOAD_LDS16(Bb + s1, b_lds[0] + db1);
  __syncthreads();
  f32x4 acc[4] = {};
  int rowA = wv * 16 + (lane & 15);
  int rowB0 = lane & 15;
  int kb2 = (lane >> 4) * 16;
  for (int it = 0; it < NT; ++it) {
    int buf = it & 1;
    if (it + 1 < NT) {
      const unsigned short* As = Ab + (it + 1) * 64;
      const unsigned short* Bs = Bb + (it + 1) * 64;
      GLOAD_LDS16(As + s0, a_lds[buf ^ 1] + db0);
      GLOAD_LDS16(As + s1, a_lds[buf ^ 1] + db1);
      GLOAD_LDS16(Bs + s0, b_lds[buf ^ 1] + db0);
      GLOAD_LDS16(Bs + s1, b_lds[buf ^ 1] + db1);
    }
#pragma unroll
    for (int kk = 0; kk < 2; ++kk) {
      s16x8 av = *tile_read_ptr(a_lds[buf], rowA, kk * 64 + kb2);
#pragma unroll
      for (int nf = 0; nf < 4; ++nf) {
        s16x8 bv = *tile_read_ptr(b_lds[buf], nf * 16 + rowB0, kk * 64 + kb2);
        acc[nf] = __builtin_amdgcn_mfma_f32_16x16x32_bf16(av, bv, acc[nf], 0, 0, 0);
      }
    }
    __syncthreads();
  }
  // ---- epilogue 1 ----
  float sp[4] = {}, dp[4] = {};
#pragma unroll
  for (int nf = 0; nf < 4; ++nf) {
    int c = nf * 16 + (lane & 15);
    float as = a_src[rh * 64 + c], ad = a_dst[rh * 64 + c];
#pragma unroll
    for (int reg = 0; reg < 4; ++reg) {
      float x = acc[nf][reg];
      x = fminf(fmaxf(x, -30.f), 30.f);
      float e2 = __builtin_amdgcn_exp2f(x * (2.f * LOG2E));
      float th = (e2 - 1.f) * __builtin_amdgcn_rcpf(e2 + 1.f);
      sp[reg] += th * as;
      dp[reg] += th * ad;
    }
  }
#pragma unroll
  for (int reg = 0; reg < 4; ++reg) {
#pragma unroll
    for (int off = 8; off; off >>= 1) {
      sp[reg] += __shfl_xor(sp[reg], off);
      dp[reg] += __shfl_xor(dp[reg], off);
    }
  }
  if ((lane & 15) == 0) {
#pragma unroll
    for (int reg = 0; reg < 4; ++reg) {
      int m = tile * 64 + wv * 16 + (lane >> 4) * 4 + reg;
      float sv = sp[reg] * LOG2E, dv = dp[reg] * LOG2E;
      sT[(size_t)P * NN * HH + (size_t)m * HH + h] =
          make_float2(__builtin_amdgcn_exp2f(sv), __builtin_amdgcn_exp2f(0.2f * sv));
      float Ed = __builtin_amdgcn_exp2f(dv), Ed2 = __builtin_amdgcn_exp2f(0.2f * dv);
      dT[((size_t)P * HH + h) * NN + m] =
          ((unsigned int)f2b(Ed) << 16) | (unsigned int)f2b(Ed2);
    }
  }
  // ---- epilogue 2: transpose-cast to hpT via LDS bounce -------------------
  unsigned short* tr = a_lds[0];
#pragma unroll
  for (int nf = 0; nf < 4; ++nf) {
    int c = nf * 16 + (lane & 15);
#pragma unroll
    for (int reg = 0; reg < 4; ++reg) {
      int m = wv * 16 + (lane >> 4) * 4 + reg;
      tr[c * 76 + m] = f2b(acc[nf][reg]);
    }
  }
  __syncthreads();
  unsigned short* dst = hpT + ((size_t)P * HH + h) * 64 * NN + tile * 64;
#pragma unroll
  for (int q = 0; q < 2; ++q) {
    int e = q * 256 + t;
    int o = e >> 3, j8 = (e & 7) * 8;
    u16x8 v;
#pragma unroll
    for (int z = 0; z < 8; ++z) v[z] = tr[o * 76 + j8 + z];
    *(u16x8*)&dst[(size_t)o * NN + j8] = v;
  }
}

// ---------------- fused GEMM K=512, 512t, K-split, merged r -----------------
// grid (NN/64, HH, BSZ*NADJ).  DMA staging, pre-swizzled source.
__global__ __launch_bounds__(512) void k_gemm_fused_ks(
    const unsigned short* __restrict__ A, const unsigned short* __restrict__ Bw,
    const float* __restrict__ a_src, const float* __restrict__ a_dst,
    unsigned short* __restrict__ hpT, float2* __restrict__ sT,
    unsigned int* __restrict__ dT) {
  __shared__ unsigned short a_lds[2][2][64 * 64];   // [group][dbuf]
  __shared__ unsigned short b_lds[2][2][64 * 64];
  const int K = K1;
  int tile = blockIdx.x, h = blockIdx.y, P = blockIdx.z;
  int rh = (P & 1) * HH + h;
  int t = threadIdx.x, lane = t & 63;
  int wid = t >> 6, g = wid >> 2, wv = wid & 3;
  int tg = t & 255;
  const unsigned short* Ab = A + ((size_t)P * NN + tile * 64) * K + g * 256;
  const unsigned short* Bb = Bw + (size_t)rh * 64 * K + g * 256;
  const int NT = 4;
  int i0 = tg, i1 = 256 + tg;
  int o0 = i0 >> 3, o1 = i1 >> 3;
  size_t s0 = (size_t)o0 * K + (size_t)(((i0 & 7) ^ (o0 & 7)) * 8);
  size_t s1 = (size_t)o1 * K + (size_t)(((i1 & 7) ^ (o1 & 7)) * 8);
  int db0 = (wv * 64) * 8, db1 = (256 + wv * 64) * 8;

  GLOAD_LDS16(Ab + s0, a_lds[g][0] + db0);
  GLOAD_LDS16(Ab + s1, a_lds[g][0] + db1);
  GLOAD_LDS16(Bb + s0, b_lds[g][0] + db0);
  GLOAD_LDS16(Bb + s1, b_lds[g][0] + db1);
  __syncthreads();
  f32x4 acc[4] = {};
  int rowA = wv * 16 + (lane & 15);
  int rowB0 = lane & 15;
  int kb2 = (lane >> 4) * 16;
  for (int it = 0; it < NT; ++it) {
    int buf = it & 1;
    if (it + 1 < NT) {
      const unsigned short* As = Ab + (it + 1) * 64;
      const unsigned short* Bs = Bb + (it + 1) * 64;
      GLOAD_LDS16(As + s0, a_lds[g][buf ^ 1] + db0);
      GLOAD_LDS16(As + s1, a_lds[g][buf ^ 1] + db1);
      GLOAD_LDS16(Bs + s0, b_lds[g][buf ^ 1] + db0);
      GLOAD_LDS16(Bs + s1, b_lds[g][buf ^ 1] + db1);
    }
#pragma unroll
    for (int kk = 0; kk < 2; ++kk) {
      s16x8 av = *tile_read_ptr(a_lds[g][buf], rowA, kk * 64 + kb2);
#pragma unroll
      for (int nf = 0; nf < 4; ++nf) {
        s16x8 bv = *tile_read_ptr(b_lds[g][buf], nf * 16 + rowB0, kk * 64 + kb2);
        acc[nf] = __builtin_amdgcn_mfma_f32_16x16x32_bf16(av, bv, acc[nf], 0, 0, 0);
      }
    }
    __syncthreads();
  }
  // ---- combine partials ----
  float* comb = (float*)&a_lds[0][0][0];
  if (g == 1) {
    float* dst = comb + (wv * 64 + lane) * 17;
#pragma unroll
    for (int nf = 0; nf < 4; ++nf)
#pragma unroll
      for (int reg = 0; reg < 4; ++reg) dst[nf * 4 + reg] = acc[nf][reg];
  }
  __syncthreads();
  if (g == 0) {
    const float* srcp = comb + (wv * 64 + lane) * 17;
#pragma unroll
    for (int nf = 0; nf < 4; ++nf)
#pragma unroll
      for (int reg = 0; reg < 4; ++reg) acc[nf][reg] += srcp[nf * 4 + reg];
    float sp[4] = {}, dp[4] = {};
#pragma unroll
    for (int nf = 0; nf < 4; ++nf) {
      int c = nf * 16 + (lane & 15);
      float as = a_src[rh * 64 + c], ad = a_dst[rh * 64 + c];
#pragma unroll
      for (int reg = 0; reg < 4; ++reg) {
        float x = acc[nf][reg];
        x = fminf(fmaxf(x, -30.f), 30.f);
        float e2 = __builtin_amdgcn_exp2f(x * (2.f * LOG2E));
        float th = (e2 - 1.f) * __builtin_amdgcn_rcpf(e2 + 1.f);
        sp[reg] += th * as;
        dp[reg] += th * ad;
      }
    }
#pragma unroll
    for (int reg = 0; reg < 4; ++reg) {
#pragma unroll
      for (int off = 8; off; off >>= 1) {
        sp[reg] += __shfl_xor(sp[reg], off);
        dp[reg] += __shfl_xor(dp[reg], off);
      }
    }
    if ((lane & 15) == 0) {
#pragma unroll
      for (int reg = 0; reg < 4; ++reg) {
        int m = tile * 64 + wv * 16 + (lane >> 4) * 4 + reg;
        float sv = sp[reg] * LOG2E, dv = dp[reg] * LOG2E;
        sT[(size_t)P * NN * HH + (size_t)m * HH + h] =
            make_float2(__builtin_amdgcn_exp2f(sv), __builtin_amdgcn_exp2f(0.2f * sv));
        float Ed = __builtin_amdgcn_exp2f(dv), Ed2 = __builtin_amdgcn_exp2f(0.2f * dv);
        dT[((size_t)P * HH + h) * NN + m] =
            ((unsigned int)f2b(Ed) << 16) | (unsigned int)f2b(Ed2);
      }
    }
    unsigned short* tr = (unsigned short*)&b_lds[0][0][0];
#pragma unroll
    for (int nf = 0; nf < 4; ++nf) {
      int c = nf * 16 + (lane & 15);
#pragma unroll
      for (int reg = 0; reg < 4; ++reg) {
        int m = wv * 16 + (lane >> 4) * 4 + reg;
        tr[c * 76 + m] = f2b(acc[nf][reg]);
      }
    }
  }
  __syncthreads();
  if (g == 0) {
    const unsigned short* tr = (const unsigned short*)&b_lds[0][0][0];
    unsigned short* dst = hpT + ((size_t)P * HH + h) * 64 * NN + tile * 64;
#pragma unroll
    for (int q = 0; q < 2; ++q) {
      int e = q * 256 + tg;
      int o = e >> 3, j8 = (e & 7) * 8;
      u16x8 v;
#pragma unroll
      for (int z = 0; z < 8; ++z) v[z] = tr[o * 76 + j8 + z];
      *(u16x8*)&dst[(size_t)o * NN + j8] = v;
    }
  }
}

// ---------------- PV (16x16x32, 512t: 2 j-halves x 4 row-waves, BK=64) ------
// hp via global_load_lds (pre-swizzled src); FULL d-half preloaded (packed);
// weight = max(Es*Ed, Es2*Ed2) & mask (Ed read unmasked-low: <=0.2% rel err,
// below bf16 quantization); l via ones-column MFMA; T5 setprio on MFMA.
// LDS 40KB -> 4 blocks/CU. grid (NN/64, HH, NP).
// MODE 0: aoutB bf16 [P,h,n,o].  MODE 1: hmidB bf16 [P,n,h*64+o] with ELU.
template <int MODE>
__global__ __launch_bounds__(512) void k_pv(
    const unsigned long long* __restrict__ bits,
    const unsigned short* __restrict__ hpT,
    const float2* __restrict__ sT, const unsigned int* __restrict__ dT,
    unsigned short* __restrict__ outB) {
  __shared__ unsigned short hp_lds[2][2][64 * 64];   // [g][dbuf] 32KB
  __shared__ unsigned int d_all[2][1024];            // full packed d half, 8KB
  int i0 = blockIdx.x * 64, h = blockIdx.y, P = blockIdx.z;
  int t = threadIdx.x, lane = t & 63;
  int wid = t >> 6, g = wid >> 2, wv = wid & 3;
  int tg = t & 255;
  int rowi = wv * 16 + (lane & 15);
  int kb = (lane >> 4) * 8;
  float2 se = sT[(size_t)P * NN * HH + (size_t)(i0 + rowi) * HH + h];
  float Es = se.x, Es2 = se.y;
  const unsigned long long* brow =
      bits + ((size_t)P * NN + i0 + rowi) * 32 + g * 16;
  const unsigned short* hpTb = hpT + ((size_t)P * HH + h) * 64 * NN + g * 1024;
  const unsigned int* dTb = dT + ((size_t)P * HH + h) * NN + g * 1024;
  f32x4 acc[4] = {};
  f32x4 accl = {};
  const short ONE = (short)0x3F80;
  const s16x8 ones = {ONE, ONE, ONE, ONE, ONE, ONE, ONE, ONE};

  // per-lane swizzled global source offsets for the 2 chunks this wave DMAs
  int idx0 = (wv * 2 + 0) * 64 + lane;
  int idx1 = (wv * 2 + 1) * 64 + lane;
  int o0 = idx0 >> 3, o1 = idx1 >> 3;
  size_t soff0 = (size_t)o0 * NN + (size_t)(((idx0 & 7) ^ (o0 & 7)) * 8);
  size_t soff1 = (size_t)o1 * NN + (size_t)(((idx1 & 7) ^ (o1 & 7)) * 8);
  unsigned short* c0  = hp_lds[g][0] + (wv * 2 + 0) * 512;
  unsigned short* c1  = hp_lds[g][0] + (wv * 2 + 1) * 512;
  unsigned short* c0b = hp_lds[g][1] + (wv * 2 + 0) * 512;
  unsigned short* c1b = hp_lds[g][1] + (wv * 2 + 1) * 512;

  // prologue: DMA tile 0; preload ENTIRE d half (4KB/group)
  GLOAD_LDS16(hpTb + soff0, c0);
  GLOAD_LDS16(hpTb + soff1, c1);
  {
    uint4 dv4 = *(const uint4*)&dTb[tg * 4];
    *(uint4*)&d_all[g][tg * 4] = dv4;
  }
  unsigned long long bw = brow[0];
  __syncthreads();

  const int NT = 16;   // 16 tiles of 64 j per half
  for (int it = 0; it < NT; ++it) {
    int buf = it & 1;
    if (it + 1 < NT) {
      const unsigned short* src = hpTb + (it + 1) * 64;
      if (buf) { GLOAD_LDS16(src + soff0, c0);  GLOAD_LDS16(src + soff1, c1); }
      else     { GLOAD_LDS16(src + soff0, c0b); GLOAD_LDS16(src + soff1, c1b); }
    }
    unsigned long long bwn = (it + 1 < NT) ? brow[it + 1] : 0ull;
    unsigned int bsel[2];
    bsel[0] = (unsigned int)(bw >> kb);
    bsel[1] = (unsigned int)(bw >> (32 + kb));
    union { unsigned int u[4]; s16x8 v; } af[2];
#pragma unroll
    for (int kk = 0; kk < 2; ++kk) {
      const unsigned int* dpk = &d_all[g][it * 64 + kk * 32 + kb];
      uint4 p0 = *(const uint4*)(dpk);
      uint4 p1 = *(const uint4*)(dpk + 4);
      unsigned int pk8[8] = {p0.x, p0.y, p0.z, p0.w, p1.x, p1.y, p1.z, p1.w};
      float w8[8];
#pragma unroll
      for (int c = 0; c < 8; ++c) {
        int msk = ((int)(bsel[kk] << (31 - c))) >> 31;   // adj bit -> 0/-1
        unsigned int pm = pk8[c] & (unsigned int)msk;    // masks Ed AND Ed2
        float Ed  = __uint_as_float(pm);        // low bf16(Ed2) bits = <=0.2% err
        float Ed2 = __uint_as_float(pm << 16);
        w8[c] = fmaxf(Es * Ed, Es2 * Ed2);   // exp(leaky(s+d)), monotone exp
      }
#pragma unroll
      for (int p = 0; p < 4; ++p) {
        unsigned int pk;
        asm("v_cvt_pk_bf16_f32 %0, %1, %2"
            : "=v"(pk) : "v"(w8[2 * p]), "v"(w8[2 * p + 1]));
        af[kk].u[p] = pk;
      }
    }
    __builtin_amdgcn_s_setprio(1);
#pragma unroll
    for (int kk = 0; kk < 2; ++kk) {
#pragma unroll
      for (int nf = 0; nf < 4; ++nf) {
        s16x8 bv = *tile_read_ptr(hp_lds[g][buf], nf * 16 + (lane & 15),
                                  kk * 64 + (lane >> 4) * 16);
        acc[nf] = __builtin_amdgcn_mfma_f32_16x16x32_bf16(af[kk].v, bv, acc[nf], 0, 0, 0);
      }
      accl = __builtin_amdgcn_mfma_f32_16x16x32_bf16(af[kk].v, ones, accl, 0, 0, 0);
    }
    __builtin_amdgcn_s_setprio(0);
    bw = bwn;
    __syncthreads();
  }
  // ---- combine j-halves: g=1 -> LDS (stride-21 pad), g=0 adds + writes -----
  float* comb = (float*)&hp_lds[0][0][0];   // 256 threads x 21 floats
  if (g == 1) {
    float* dst = comb + (wv * 64 + lane) * 21;
#pragma unroll
    for (int nf = 0; nf < 4; ++nf)
#pragma unroll
      for (int reg = 0; reg < 4; ++reg) dst[nf * 4 + reg] = acc[nf][reg];
#pragma unroll
    for (int reg = 0; reg < 4; ++reg) dst[16 + reg] = accl[reg];
  }
  __syncthreads();
  if (g == 0) {
    const float* srcp = comb + (wv * 64 + lane) * 21;
#pragma unroll
    for (int nf = 0; nf < 4; ++nf)
#pragma unroll
      for (int reg = 0; reg < 4; ++reg) acc[nf][reg] += srcp[nf * 4 + reg];
#pragma unroll
    for (int reg = 0; reg < 4; ++reg) accl[reg] += srcp[16 + reg];
    int col = lane & 15, r0g = (lane >> 4) * 4;
#pragma unroll
    for (int reg = 0; reg < 4; ++reg) {
      int m = wv * 16 + r0g + reg;
      float linv = 1.0f / accl[reg];
      if (MODE == 0) {
        size_t ob = (((size_t)P * HH + h) * NN + i0 + m) * 64 + col;
#pragma unroll
        for (int nf = 0; nf < 4; ++nf)
          outB[ob + nf * 16] = f2b(acc[nf][reg] * linv);
      } else {
        size_t ob = ((size_t)P * NN + i0 + m) * K1 + h * 64 + col;
#pragma unroll
        for (int nf = 0; nf < 4; ++nf) {
          float v = acc[nf][reg] * linv;
          v = v > 0.f ? v : (__builtin_amdgcn_exp2f(v * LOG2E) - 1.f);
          outB[ob + nf * 16] = f2b(v);
        }
      }
    }
  }
}

// ---------------- mean over heads → seq[b,n,r,:] (bf16 in, merged r) --------
__global__ __launch_bounds__(256) void k_mean(
    const unsigned short* __restrict__ in, float* __restrict__ seq) {
  int idx = blockIdx.x * 256 + threadIdx.x;   // over BSZ*NADJ*NN*8
  int o8 = (idx & 7) * 8;
  int n = (idx >> 3) & (NN - 1);
  int P = idx >> 14;
  int b = P >> 1, r = P & 1;
  float acc[8] = {};
#pragma unroll
  for (int h = 0; h < HH; ++h) {
    u16x8 v = *(const u16x8*)&in[(((size_t)P * HH + h) * NN + n) * 64 + o8];
#pragma unroll
    for (int z = 0; z < 8; ++z) acc[z] += b2f((unsigned short)v[z]);
  }
  float* dst = &seq[(((size_t)b * NN + n) * NADJ + r) * 64 + o8];
#pragma unroll
  for (int z = 0; z < 8; ++z) dst[z] = acc[z] * 0.125f;
}

// ---------------- final: fproj (feat@aw1) + fusion + log_softmax ------------
__global__ __launch_bounds__(256) void k_fuse(
    const unsigned short* __restrict__ featB, const float* __restrict__ aw1,
    const float* __restrict__ seq, const float* __restrict__ aw2,
    const float* __restrict__ am, float* __restrict__ outp) {
  __shared__ float w2[64][65];
  __shared__ float a1[NF][64];
  __shared__ float amv[64];
  __shared__ unsigned short feat_l[4][NF];
  __shared__ float seq_lds[4][NADJ][64];
  int t = threadIdx.x;
#pragma unroll
  for (int q = 0; q < 16; ++q) {
    int e = t + 256 * q;
    w2[e >> 6][e & 63] = aw2[e];
  }
  float* a1f = &a1[0][0];
#pragma unroll
  for (int q = 0; q < 12; ++q) {
    int e4 = (t + 256 * q) * 4;
    *(float4*)&a1f[e4] = *(const float4*)&aw1[e4];
  }
  if (t < 64) amv[t] = am[t];
  int wid = t >> 6, lane = t & 63;
  int bn = blockIdx.x * 4 + wid;               // over BSZ*NN
  if (lane < 24)
    *(u16x8*)&feat_l[wid][lane * 8] = *(const u16x8*)&featB[(size_t)bn * NF + lane * 8];
  float s0 = seq[((size_t)bn * NADJ + 0) * 64 + lane];
  float s1 = seq[((size_t)bn * NADJ + 1) * 64 + lane];
  seq_lds[wid][0][lane] = s0;
  seq_lds[wid][1][lane] = s1;
  __syncthreads();
  float f = 0.f;
#pragma unroll 4
  for (int kc = 0; kc < NF / 8; ++kc) {
    u16x8 fv = *(const u16x8*)&feat_l[wid][kc * 8];
#pragma unroll
    for (int z = 0; z < 8; ++z)
      f += b2f((unsigned short)fv[z]) * a1[kc * 8 + z][lane];
  }
  float q0 = f, q1 = f;
  for (int k = 0; k < 64; ++k) {
    float wv = w2[k][lane];
    q0 += seq_lds[wid][0][k] * wv;
    q1 += seq_lds[wid][1][k] * wv;
  }
  q0 = tanhf(q0); q1 = tanhf(q1);
  float sc0 = q0 * amv[lane], sc1 = q1 * amv[lane];
  for (int off = 32; off; off >>= 1) {
    sc0 += __shfl_xor(sc0, off);
    sc1 += __shfl_xor(sc1, off);
  }
  float mx = fmaxf(sc0, sc1);
  float e0 = __expf(sc0 - mx), e1 = __expf(sc1 - mx);
  float inv = 1.f / (e0 + e1);
  float fu = (e0 * inv) * s0 + (e1 * inv) * s1;
  float m = fu;
  for (int off = 32; off; off >>= 1) m = fmaxf(m, __shfl_xor(m, off));
  float ex = __expf(fu - m);
  float ssum = ex;
  for (int off = 32; off; off >>= 1) ssum += __shfl_xor(ssum, off);
  outp[(size_t)bn * 64 + lane] = fu - m - __logf(ssum);
}

extern "C" void kernel_launch(void* const* d_in, const int* in_sizes, int n_in,
                              void* d_out, int out_size, void* d_ws, size_t ws_size,
                              hipStream_t stream) {
  (void)in_sizes; (void)n_in; (void)out_size; (void)ws_size;
  const float* hg   = (const float*)d_in[0];
  const int*   vert = (const int*)d_in[1];
  const float* lemb = (const float*)d_in[2];
  const float* emb0 = (const float*)d_in[3];
  const float* emb1 = (const float*)d_in[4];
  const float* w_l0 = (const float*)d_in[5];
  const float* as0  = (const float*)d_in[6];
  const float* ad0  = (const float*)d_in[7];
  const float* w_l1 = (const float*)d_in[8];
  const float* as1  = (const float*)d_in[9];
  const float* ad1  = (const float*)d_in[10];
  const float* aw1  = (const float*)d_in[11];
  const float* aw2  = (const float*)d_in[12];
  const float* am   = (const float*)d_in[13];
  float* out = (float*)d_out;

  const int NP = BSZ * NADJ;   // 4 planes
  char* p = (char*)d_ws;
  unsigned short* hpT   = (unsigned short*)p;  p += (size_t)NP*HH*NN*64*2;    // 8MB
  unsigned short* aoutB = (unsigned short*)p;  p += (size_t)NP*HH*NN*64*2;    // 8MB
  unsigned short* hmidB = (unsigned short*)p;  p += (size_t)NP*NN*K1*2;       // 8MB
  unsigned short* featB = (unsigned short*)p;  p += (size_t)BSZ*NN*NF*2;      // 1.5MB
  unsigned short* wT0   = (unsigned short*)p;  p += (size_t)NADJ*HH*64*NF*2;
  unsigned short* wT1   = (unsigned short*)p;  p += (size_t)NADJ*HH*64*K1*2;
  float2* sT            = (float2*)p;          p += (size_t)NP*NN*HH*8;       // 1MB
  unsigned int* dT      = (unsigned int*)p;    p += (size_t)NP*HH*NN*4;       // 0.5MB
  unsigned long long* bits = (unsigned long long*)p; p += (size_t)NP*NN*(NN/64)*8;  // 2MB
  float* seq            = (float*)p;           p += (size_t)BSZ*NN*NADJ*64*4; // 2MB

  // one-time prep
  k_build_feat<<<(BSZ*NN*NF)/256, 256, 0, stream>>>(vert, lemb, emb0, emb1, featB);
  k_bits<<<(size_t)NP*NN*NN/256, 256, 0, stream>>>(hg, bits);
  k_tcast<<<dim3(NF/64, NADJ*HH), 256, 0, stream>>>(w_l0, wT0, NF);
  k_tcast<<<dim3(K1/64, NADJ*HH), 256, 0, stream>>>(w_l1, wT1, K1);

  // merged r=0/r=1 pipeline: 5 dispatches
  k_gemm_fused<NF><<<dim3(NN/64, NADJ*HH, BSZ), 256, 0, stream>>>(
      featB, wT0, as0, ad0, hpT, sT, dT);
  k_pv<1><<<dim3(NN/64, HH, NP), 512, 0, stream>>>(bits, hpT, sT, dT, hmidB);
  k_gemm_fused_ks<<<dim3(NN/64, HH, NP), 512, 0, stream>>>(
      hmidB, wT1, as1, ad1, hpT, sT, dT);
  k_pv<0><<<dim3(NN/64, HH, NP), 512, 0, stream>>>(bits, hpT, sT, dT, aoutB);
  k_mean<<<(NP*NN*8)/256, 256, 0, stream>>>(aoutB, seq);

  k_fuse<<<BSZ*NN/4, 256, 0, stream>>>(featB, aw1, seq, aw2, am, out);
}